// Round 5
// baseline (2024.078 us; speedup 1.0000x reference)
//
#include <hip/hip_runtime.h>
#include <stdint.h>

// BitSwarmLinear: out = x @ sign(population.sum(axis=2))^T
//   x:          (4, 4096, 2048) fp32  -> A, M=16384, K=2048
//   population: (2048, 2048, 32) fp32 -> reduced+signed -> W (N=2048, K=2048), ±1
//   out:        (4, 4096, 2048) fp32  -> C, M x N
//
// v6: 2 BLOCKS/CU (break the barrier lockstep). BK 64->32 halves LDS to
//     64 KiB/block -> 2 independent blocks co-resident per CU (4 waves/SIMD).
//     One block's read region overlaps the other's MFMA cluster, filling the
//     matrix pipe toward the LDS-read-bound ceiling (~63%). Traffic and MFMA
//     counts unchanged. Swizzle re-derived for 64 B rows:
//     byte ^= ((byte>>7)&3)<<4 (global source + read side, involution).
//     Counted vmcnt(4) boundary; A-prefetch in phase-1 read region, B after
//     its death barrier. 2 phases/tile, 16 MFMA each.

static constexpr int M_DIM = 16384;
static constexpr int N_DIM = 2048;
static constexpr int K_DIM = 2048;
static constexpr int SWARM = 32;

typedef __attribute__((ext_vector_type(8))) short short8;   // 8 x bf16 = 4 VGPRs
typedef __attribute__((ext_vector_type(4))) float f32x4;    // MFMA accumulator

// ---------------------------------------------------------------------------
// Kernel 1: swarm reduction + sign binarization (memory-bound, ~85 us floor).
// ---------------------------------------------------------------------------
__global__ __launch_bounds__(256) void swarm_reduce(const float4* __restrict__ pop4,
                                                    ushort* __restrict__ W) {
    const int tid = blockIdx.x * 256 + threadIdx.x;   // one float4 per thread
    float4 v = pop4[tid];
    float s = v.x + v.y + v.z + v.w;
    s += __shfl_xor(s, 1);
    s += __shfl_xor(s, 2);
    s += __shfl_xor(s, 4);
    if ((threadIdx.x & 7) == 0) {
        // +1.0 bf16 = 0x3F80, -1.0 bf16 = 0xBF80 (exact)
        W[tid >> 3] = (s >= 0.0f) ? (ushort)0x3F80 : (ushort)0xBF80;
    }
}

// fp32 -> bf16 round-to-nearest-even (no NaN inputs here)
__device__ __forceinline__ ushort f2bf(float f) {
    uint32_t u = __float_as_uint(f);
    u += 0x7FFFu + ((u >> 16) & 1u);
    return (ushort)(u >> 16);
}

// ---------------------------------------------------------------------------
// Kernel 2: one-shot fp32 -> bf16 conversion of x (~33 us, streaming).
// ---------------------------------------------------------------------------
__global__ __launch_bounds__(256) void a_to_bf16(const float4* __restrict__ in,
                                                 ushort* __restrict__ out) {
    const int i = blockIdx.x * 256 + threadIdx.x;     // one 8-float group
    float4 v0 = in[2 * i];
    float4 v1 = in[2 * i + 1];
    union { ushort s[8]; uint4 u; } pk;
    pk.s[0] = f2bf(v0.x);
    pk.s[1] = f2bf(v0.y);
    pk.s[2] = f2bf(v0.z);
    pk.s[3] = f2bf(v0.w);
    pk.s[4] = f2bf(v1.x);
    pk.s[5] = f2bf(v1.y);
    pk.s[6] = f2bf(v1.z);
    pk.s[7] = f2bf(v1.w);
    *(uint4*)(&out[(size_t)i * 8]) = pk.u;            // 16 B aligned store
}

// ---------------------------------------------------------------------------
// Kernel 3: 256x256 bf16 MFMA GEMM, BK=32, 2 blocks/CU.
//   - 512 threads = 8 waves in 2(M) x 4(N); per-wave output 128x64.
//   - LDS 64 KiB: double-buffered [256][32] bf16 tiles for A and B.
//   - Swizzle: byte ^= ((byte>>7)&3)<<4 (XOR row bits 1-2 into the 16B-slot
//     bits of the 64 B row). 16 lanes/quad cover all 8 bank-slot positions
//     2-way (free). Applied on the GLOBAL source (LDS dest linear) and on
//     every ds_read address (read flip = ((l16>>1)&3)<<4, constant/thread).
//   - 2 phases/K-tile, 16 MFMA (16x16x32) each; counted vmcnt(4) boundary.
// Fragment layouts (HW-verified, guide §3):
//   A[m = lane&15][k = 8*(lane>>4) + j]   B[k = 8*(lane>>4)+j][n = lane&15]
//   D[i = 4*(lane>>4) + r][j = lane&15]
// ---------------------------------------------------------------------------
#define BM 256
#define BN 256
#define BK 32
#define NT (K_DIM / BK)          // 64 K-tiles
#define TILE_E (BM * BK)         // 8192 ushort = 16 KiB per tile

__device__ __forceinline__ void stage_tile(const ushort* __restrict__ G,
                                           ushort* dst, int k0, int t) {
    #pragma unroll
    for (int i = 0; i < 2; ++i) {
        const int q  = (i * 512 + t) * 16;             // linear LDS byte offset
        const int sq = q ^ (((q >> 7) & 3) << 4);      // 2-bit row->slot XOR
        const int row  = sq >> 6;                      // == q >> 6 (bits 6+ untouched)
        const int colb = sq & 63;
        __builtin_amdgcn_global_load_lds(
            (const __attribute__((address_space(1))) void*)
                (G + (size_t)row * K_DIM + k0 + (colb >> 1)),
            (__attribute__((address_space(3))) void*)((char*)dst + q),
            16, 0, 0);
    }
}

// swizzled fragment read: row stride 64 B; flip = ((l16>>1)&3)<<4 == the
// staging swizzle for row = 16c + l16 (16c contributes 0 mod 4 to row>>1).
#define RD(base, row, qoff, flip) \
    (*(const short8*)((base) + ((row) * 64) + ((qoff) ^ (flip))))

#define PHASE_OPEN()                                          \
    __builtin_amdgcn_s_barrier();                             \
    asm volatile("s_waitcnt lgkmcnt(0)" ::: "memory");        \
    __builtin_amdgcn_sched_barrier(0);                        \
    __builtin_amdgcn_s_setprio(1);

__global__ __launch_bounds__(512, 4) void gemm_bt(const ushort* __restrict__ A,
                                                  const ushort* __restrict__ B,
                                                  float* __restrict__ C) {
    // [buf0 A][buf0 B][buf1 A][buf1 B]  = 64 KiB
    __shared__ ushort lds[4 * TILE_E];

    const int t    = threadIdx.x;         // 0..511
    const int wave = t >> 6;
    const int lane = t & 63;
    const int wmid = wave >> 2;           // 0..1  (M)
    const int wnid = wave & 3;            // 0..3  (N)
    const int l16  = lane & 15;
    const int quad = lane >> 4;
    const int qoff = quad * 16;
    const int flip = ((l16 >> 1) & 3) << 4;

    // XCD-aware grid: blocks with bid%8==k share XCD k and the bn=k W panel
    // (1 MB, L2-resident); bm streams A panels through L3.
    const int bid = blockIdx.x;           // 0..511
    const int bn  = bid & 7;
    const int bm  = bid >> 3;

    const ushort* At = A + (size_t)(bm * BM) * K_DIM;
    const ushort* Bt = B + (size_t)(bn * BN) * K_DIM;

    f32x4 acc[8][4];
    #pragma unroll
    for (int i = 0; i < 8; ++i)
        #pragma unroll
        for (int j = 0; j < 4; ++j)
            acc[i][j] = (f32x4){0.f, 0.f, 0.f, 0.f};

    const int rA0 = wmid * 128 + l16;     // A frag base row (mq=0)
    const int rB0 = wnid * 64 + l16;      // B frag base row (nq=0)

    // ---- prologue: tiles 0 and 1 in flight, wait only for tile 0 ----
    stage_tile(At, lds + 0 * TILE_E, 0, t);
    stage_tile(Bt, lds + 1 * TILE_E, 0, t);
    stage_tile(At, lds + 2 * TILE_E, BK, t);
    stage_tile(Bt, lds + 3 * TILE_E, BK, t);
    asm volatile("s_waitcnt vmcnt(4)" ::: "memory");   // tile 0 landed
    __builtin_amdgcn_s_barrier();

    short8 af[8], b0[2], b1[2];

    for (int kt = 0; kt < NT; ++kt) {
        ushort*     curA = lds + (kt & 1) * 2 * TILE_E;
        ushort*     curB = curA + TILE_E;
        const char* cA   = (const char*)curA;
        const char* cB   = (const char*)curB;
        const bool  pf   = (kt + 2 < NT);

        // ---- phase 0: read A (all 8 frags) + B(nh0) 2 frags; 16 MFMA ----
        #pragma unroll
        for (int mq = 0; mq < 8; ++mq)
            af[mq] = RD(cA, rA0 + mq * 16, qoff, flip);
        #pragma unroll
        for (int nq = 0; nq < 2; ++nq)
            b0[nq] = RD(cB, rB0 + nq * 16, qoff, flip);
        PHASE_OPEN()
        #pragma unroll
        for (int mq = 0; mq < 8; ++mq)
            #pragma unroll
            for (int nq = 0; nq < 2; ++nq)
                acc[mq][nq] = __builtin_amdgcn_mfma_f32_16x16x32_bf16(
                    af[mq], b0[nq], acc[mq][nq], 0, 0, 0);
        __builtin_amdgcn_s_setprio(0);
        __builtin_amdgcn_s_barrier();     // A + b0 reads all complete -> curA dead after here

        // ---- phase 1: read B(nh1) 2 frags; A-prefetch kt+2 (curA dead) ----
        #pragma unroll
        for (int nq = 0; nq < 2; ++nq)
            b1[nq] = RD(cB, rB0 + 32 + nq * 16, qoff, flip);
        if (pf) {
            asm volatile("" ::: "memory");
            stage_tile(At, curA, (kt + 2) * BK, t);
        }
        PHASE_OPEN()
        #pragma unroll
        for (int mq = 0; mq < 8; ++mq)
            #pragma unroll
            for (int nq = 0; nq < 2; ++nq)
                acc[mq][2 + nq] = __builtin_amdgcn_mfma_f32_16x16x32_bf16(
                    af[mq], b1[nq], acc[mq][2 + nq], 0, 0, 0);
        __builtin_amdgcn_s_setprio(0);
        __builtin_amdgcn_s_barrier();     // b1 reads complete -> curB dead

        // ---- boundary: B-prefetch kt+2, counted wait, sync ----
        if (pf) {
            asm volatile("" ::: "memory");
            stage_tile(Bt, curB, (kt + 2) * BK, t);
            asm volatile("s_waitcnt vmcnt(4)" ::: "memory");  // kt+1 landed
        } else {
            asm volatile("s_waitcnt vmcnt(0)" ::: "memory");
        }
        __builtin_amdgcn_s_barrier();
    }

    // ---- epilogue: D[i = 4*quad + r][j = l16] ----
    const int row_base = bm * BM + wmid * 128 + quad * 4;
    const int col_base = bn * BN + wnid * 64 + l16;
    #pragma unroll
    for (int mi = 0; mi < 8; ++mi) {
        #pragma unroll
        for (int ni = 0; ni < 4; ++ni) {
            const int row0 = row_base + mi * 16;
            const int col  = col_base + ni * 16;
            #pragma unroll
            for (int r = 0; r < 4; ++r)
                C[(size_t)(row0 + r) * N_DIM + col] = acc[mi][ni][r];
        }
    }
}

extern "C" void kernel_launch(void* const* d_in, const int* in_sizes, int n_in,
                              void* d_out, int out_size, void* d_ws, size_t ws_size,
                              hipStream_t stream) {
    const float* x   = (const float*)d_in[0];   // (4,4096,2048) fp32
    const float* pop = (const float*)d_in[1];   // (2048,2048,32) fp32
    float* out = (float*)d_out;

    // workspace layout: [W bf16: 8 MiB][A bf16: 64 MiB]
    ushort* W   = (ushort*)d_ws;
    ushort* Abf = (ushort*)d_ws + (size_t)N_DIM * K_DIM;

    // Phase 1: reduce population -> W (±1 bf16)
    const int total4 = N_DIM * K_DIM * SWARM / 4;     // 33,554,432 float4 loads
    swarm_reduce<<<total4 / 256, 256, 0, stream>>>((const float4*)pop, W);

    // Phase 2: x fp32 -> bf16 (one pass)
    const int groups = M_DIM * K_DIM / 8;             // 4,194,304 8-float groups
    a_to_bf16<<<groups / 256, 256, 0, stream>>>((const float4*)x, Abf);

    // Phase 3: C = x @ W^T via bf16 MFMA (2 blocks/CU)
    gemm_bt<<<(M_DIM / BM) * (N_DIM / BN), 512, 0, stream>>>(Abf, W, out);
}